// Round 13
// baseline (197.317 us; speedup 1.0000x reference)
//
#include <hip/hip_runtime.h>
#include <hip/hip_bf16.h>
#include <cstdint>

#define D_MODEL 1024
#define NUM_HEADS 16
#define HEAD_DIM 64
#define BATCH 2
#define SEQ 2048
#define MROWS (BATCH * SEQ)  // 4096

typedef __attribute__((ext_vector_type(8))) short bf16x8;   // 8 bf16 in 4 VGPRs
typedef __attribute__((ext_vector_type(4))) float f32x4;
typedef __attribute__((ext_vector_type(2))) unsigned u32x2;
typedef unsigned short u16;

// Q is pre-scaled by 0.125 * log2(e) at the QKV epilogue, so attention scores
// come out of the MFMA already in log2 domain: p = exp2(s) directly.
#define QSCALE (0.125f * 1.44269504f)

#if __has_builtin(__builtin_amdgcn_exp2f)
#define EXP2F(x) __builtin_amdgcn_exp2f(x)
#else
#define EXP2F(x) exp2f(x)
#endif

static __device__ __forceinline__ u16 f2bf(float f) {
    unsigned int u = __float_as_uint(f);
    unsigned int lsb = (u >> 16) & 1u;
    u += 0x7fffu + lsb;
    return (u16)(u >> 16);
}

// pack two fp32 -> two bf16 in one dword
#if __has_builtin(__builtin_amdgcn_cvt_pk_bf16_f32)
static __device__ __forceinline__ unsigned pkbf(float a, float b) {
    typedef __attribute__((ext_vector_type(2))) __bf16 bf2;
    union { bf2 v; unsigned u; } cv;
    cv.v = __builtin_amdgcn_cvt_pk_bf16_f32(a, b);
    return cv.u;
}
#else
static __device__ __forceinline__ unsigned pkbf(float a, float b) {
    unsigned ua = (__float_as_uint(a) + 0x8000u) >> 16;
    unsigned ub = (__float_as_uint(b) + 0x8000u) & 0xffff0000u;
    return ua | ub;
}
#endif

// ---- lane-quad swaps for in-register P redistribution (verified R10/R11) ----
// permlane32_swap: a' = [a0,a1,b0,b1] (by 16-lane quads), b' = [a2,a3,b2,b3]
// permlane16_swap: a' = [a0,b0,a2,b2],                    b' = [a1,b1,a3,b3]
#if __has_builtin(__builtin_amdgcn_permlane32_swap)
static __device__ __forceinline__ void plswap32(unsigned &a, unsigned &b) {
    u32x2 r = __builtin_amdgcn_permlane32_swap(a, b, false, false);
    a = r[0]; b = r[1];
}
#else
static __device__ __forceinline__ void plswap32(unsigned &a, unsigned &b) {
    const bool lo = ((threadIdx.x & 63) < 32);
    unsigned sa = __shfl_xor((int)a, 32, 64), sb = __shfl_xor((int)b, 32, 64);
    unsigned na = lo ? a : sb;
    unsigned nb = lo ? sa : b;
    a = na; b = nb;
}
#endif
#if __has_builtin(__builtin_amdgcn_permlane16_swap)
static __device__ __forceinline__ void plswap16(unsigned &a, unsigned &b) {
    u32x2 r = __builtin_amdgcn_permlane16_swap(a, b, false, false);
    a = r[0]; b = r[1];
}
#else
static __device__ __forceinline__ void plswap16(unsigned &a, unsigned &b) {
    const bool ev = (((threadIdx.x & 63) >> 4) & 1) == 0;
    unsigned sa = __shfl_xor((int)a, 16, 64), sb = __shfl_xor((int)b, 16, 64);
    unsigned na = ev ? a : sb;
    unsigned nb = ev ? sa : b;
    a = na; b = nb;
}
#endif

static __device__ __forceinline__ void gload_lds16(const void* g, void* l) {
    // 16B/lane direct global->LDS; LDS dest = wave-uniform base + lane*16
    __builtin_amdgcn_global_load_lds((const __attribute__((address_space(1))) unsigned int*)g,
                                     (__attribute__((address_space(3))) unsigned int*)l,
                                     16, 0, 0);
}

// ---------------------------------------------------------------- convert
__global__ void cvt_all(const float* __restrict__ x,
                        const float* __restrict__ w0, const float* __restrict__ w1,
                        const float* __restrict__ w2, const float* __restrict__ w3,
                        u16* __restrict__ base) {
    const int which = blockIdx.y;   // 0..7
    const int NE = D_MODEL * D_MODEL;  // 1M elements per chunk
    const float* s;
    if (which < 4)      s = x + (size_t)which * NE;
    else if (which == 4) s = w0;
    else if (which == 5) s = w1;
    else if (which == 6) s = w2;
    else                 s = w3;
    u16* dst = base + (size_t)which * NE;
    const int i = (blockIdx.x * blockDim.x + threadIdx.x) * 4;
    float4 v = *(const float4*)(s + i);
    ushort4 o;
    o.x = f2bf(v.x); o.y = f2bf(v.y); o.z = f2bf(v.z); o.w = f2bf(v.w);
    *(ushort4*)(dst + i) = o;
}

// ---------------------------------------------------------------- staged GEMM
// C[M,N] = A[M,K] * W[N,K]^T + bias. 128xBN tile, BK=64, global_load_lds
// staging with 16B-chunk XOR swizzle.
// MODE 0 (BN=128, fused QKV, N=3072): blocks 0-7 -> Q (pre-scaled, coalesced
// [B,H,S,64]), 8-15 -> K (coalesced), 16-23 -> V written TRANSPOSED to
// VT[B,H,64,S] via an in-LDS 128x128 transpose (two 64-row passes).
// MODE 1: fp32 row-major out (final projection). T buffer shrunk to 16 elems.
template<int BN, int MODE>
__global__ __launch_bounds__(256, 3)
void gemm_staged(const u16* __restrict__ A, const u16* __restrict__ W,
                 const float* __restrict__ b0, const float* __restrict__ b1,
                 const float* __restrict__ b2,
                 u16* __restrict__ o0, u16* __restrict__ o1, u16* __restrict__ o2,
                 float* __restrict__ of, int K, int N) {
    constexpr int WN = BN / 2;   // per-wave n extent
    constexpr int NJ = WN / 16;  // b-fragment count
    __shared__ __align__(16) u16 As[128 * 64];
    __shared__ __align__(16) u16 Bs[BN * 64];
    __shared__ __align__(16) u16 T[(MODE == 0) ? 64 * 136 : 16];  // V-transpose staging

    const int lane = threadIdx.x & 63;
    const int w    = threadIdx.x >> 6;
    const int quad = lane >> 4;
    const int l16  = lane & 15;
    const int wm = w >> 1, wn = w & 1;

    const u16* Ablk = A + (size_t)(blockIdx.y * 128) * K;
    const u16* Wblk = W + (size_t)(blockIdx.x * BN) * K;

    const int srow = lane >> 3;
    const int scol = lane & 7;

    f32x4 acc[4][NJ];
#pragma unroll
    for (int i = 0; i < 4; ++i)
#pragma unroll
        for (int j = 0; j < NJ; ++j) acc[i][j] = (f32x4){0.f, 0.f, 0.f, 0.f};

    for (int kb0 = 0; kb0 < K; kb0 += 64) {
        __syncthreads();
#pragma unroll
        for (int t = 0; t < 4; ++t) {  // A: 128 rows
            const int r  = w * 32 + t * 8 + srow;
            const int cg = scol ^ (r & 7);
            gload_lds16(Ablk + (size_t)r * K + kb0 + cg * 8, &As[(w * 32 + t * 8) * 64]);
        }
#pragma unroll
        for (int t = 0; t < BN / 32; ++t) {  // B: BN rows
            const int r  = w * (BN / 4) + t * 8 + srow;
            const int cg = scol ^ (r & 7);
            gload_lds16(Wblk + (size_t)r * K + kb0 + cg * 8, &Bs[(w * (BN / 4) + t * 8) * 64]);
        }
        __syncthreads();
#pragma unroll
        for (int ks = 0; ks < 2; ++ks) {
            bf16x8 a[4], b[NJ];
#pragma unroll
            for (int i = 0; i < 4; ++i) {
                const int ra = wm * 64 + 16 * i + l16;
                a[i] = *(const bf16x8*)&As[ra * 64 + ((ks * 4 + quad) ^ (ra & 7)) * 8];
            }
#pragma unroll
            for (int j = 0; j < NJ; ++j) {
                const int rb = wn * WN + 16 * j + l16;
                b[j] = *(const bf16x8*)&Bs[rb * 64 + ((ks * 4 + quad) ^ (rb & 7)) * 8];
            }
#pragma unroll
            for (int i = 0; i < 4; ++i)
#pragma unroll
                for (int j = 0; j < NJ; ++j)
                    acc[i][j] = __builtin_amdgcn_mfma_f32_16x16x32_bf16(a[i], b[j], acc[i][j], 0, 0, 0);
        }
    }

    const int mbase = blockIdx.y * 128 + wm * 64;
    const int nbase = blockIdx.x * BN + wn * WN;

    if (MODE == 0 && blockIdx.x >= 16) {
        // ---- V block: write VT[b][h][d][s] via in-LDS transpose ----
        const int mb    = blockIdx.y * 128;
        const int bb    = mb >> 11;        // batch (uniform per block)
        const int sbase = mb & 2047;       // s-range start (uniform)
#pragma unroll
        for (int p = 0; p < 2; ++p) {      // n-half pass
            __syncthreads();               // T free / previous pass consumed
            if (wn == p) {                 // 2 waves own this n-half
#pragma unroll
                for (int j = 0; j < NJ; ++j) {
                    const int nl = 16 * j + l16;          // local n within half
                    const float bv = b2[(nbase + 16 * j + l16) & 1023];
#pragma unroll
                    for (int i = 0; i < 4; ++i) {
                        const int ml = wm * 64 + 16 * i + quad * 4;
                        uint2 pk;
                        pk.x = pkbf(acc[i][j][0] + bv, acc[i][j][1] + bv);
                        pk.y = pkbf(acc[i][j][2] + bv, acc[i][j][3] + bv);
                        *(uint2*)&T[nl * 136 + ml] = pk;
                    }
                }
            }
            __syncthreads();
            // cooperative coalesced out: 64 rows (d) x 128 s; 256B/row
            const int row = threadIdx.x >> 2;                       // 0..63
            const int gn2 = blockIdx.x * 128 + p * 64 + row;
            const int rem2 = gn2 & 1023;
            const int h = rem2 >> 6, d = rem2 & 63;
            u16* dstrow = o2 + (((size_t)(bb * NUM_HEADS + h) * 64) + d) * SEQ + sbase;
#pragma unroll
            for (int k = 0; k < 4; ++k) {
                const int chunk = (threadIdx.x & 3) * 4 + k;        // 0..15
                *(uint4*)(dstrow + chunk * 8) = *(const uint4*)&T[row * 136 + chunk * 8];
            }
        }
        return;
    }

    if (MODE == 0) {
#pragma unroll
        for (int j = 0; j < NJ; ++j) {
            const int gn = nbase + 16 * j + l16;       // 0..2047 here (Q or K)
            const int which = gn >> 10, rem = gn & 1023;
            const float bv = (which == 0 ? b0 : b1)[rem];
            u16* dst = (which == 0) ? o0 : o1;
            const float scl = (which == 0) ? QSCALE : 1.0f;  // Q: x0.125*log2e
            const int h = rem >> 6, d = rem & 63;
#pragma unroll
            for (int i = 0; i < 4; ++i)
#pragma unroll
                for (int r = 0; r < 4; ++r) {
                    const int gm = mbase + 16 * i + quad * 4 + r;
                    const int bb = gm >> 11, s = gm & 2047;
                    dst[(((size_t)(bb * NUM_HEADS + h) * SEQ) + s) * 64 + d] =
                        f2bf((acc[i][j][r] + bv) * scl);
                }
        }
    } else {
#pragma unroll
        for (int j = 0; j < NJ; ++j) {
            const int gn = nbase + 16 * j + l16;
            const float bv = b0[gn];
#pragma unroll
            for (int i = 0; i < 4; ++i)
#pragma unroll
                for (int r = 0; r < 4; ++r) {
                    const int gm = mbase + 16 * i + quad * 4 + r;
                    of[(size_t)gm * N + gn] = acc[i][j][r] + bv;
                }
        }
    }
}

// ---------------------------------------------------------------- attention
// R19 = R17 exactly (measured best: 56.4us, 0 bank conflicts, VGPR 64).
// Attn is FROZEN: eight structural experiments (R7-R18: occupancy x2/x0.5,
// LDS reads x0.5, 2x pipeline attempts, barriers x0.5, conflicts +-4M,
// MFMA chain splits) all land at 56-72us -- latency-plateau at HIP source
// level (MfmaUtil ~24, VALU ~47, HBM ~4.7%). Remaining gap is co-designed
// schedule territory (T16), not single-lever.
// KVBLK=128 (16 tiles), K in 128B-row XOR-swizzled layout, V as two 64-key
// sub-tiles in R11's proven conflict-free layout. In-reg P via cvt_pk +
// permlane swaps, dirty bitmask (no VMEM in loop), no-clamp exp2, setprio.
__global__ __launch_bounds__(512, 4)
void attn_kernel(const u16* __restrict__ Q, const u16* __restrict__ K,
                 const u16* __restrict__ VT, const int* __restrict__ mask,
                 u16* __restrict__ ctx) {
    __shared__ __align__(16) u16 Ks[2][128 * 64];     // 128 keys x 64 d (128B rows)
    __shared__ __align__(16) u16 Vs[2][2][64 * 64];   // [buf][key-half]: 64 d x 64 keys

    const int lane = threadIdx.x & 63;
    const int w    = threadIdx.x >> 6;   // 0..7
    const int quad = lane >> 4;
    const int l16  = lane & 15;

    const int bh = blockIdx.x & 31;   // same-head q-blocks share an XCD's L2
    const int qb = blockIdx.x >> 5;   // 0..15
    const int b  = bh >> 4;
    const int h  = bh & 15;
    const int qbase = qb * 128 + w * 16;

    const u16* Qh = Q + (size_t)bh * SEQ * 64;
    const u16* Kh = K + (size_t)bh * SEQ * 64;
    const u16* Vh = VT + (size_t)bh * 64 * SEQ;
    const int* mrow = mask + b * SEQ;

    const int srow = lane >> 3;   // row within an 8-row staging group
    const int scol = lane & 7;    // stored 16B chunk slot (8 per 128B row)
    const int cg   = scol ^ srow; // global chunk for XOR-swizzled slot

    // ---- stage tile kb=0 into buffer 0 ----
    // K: wave w stages key-rows 16w..16w+15 (2 instr, R11 row pattern)
#pragma unroll
    for (int t = 0; t < 2; ++t) {
        const int r = 16 * w + 8 * t + srow;
        gload_lds16(Kh + (size_t)r * 64 + (scol ^ (r & 7)) * 8,
                    &Ks[0][(16 * w + 8 * t) * 64]);
    }
    // V: wave w stages d-rows 8w..8w+7 of each 64-key half (R11 exact pattern)
#pragma unroll
    for (int hh = 0; hh < 2; ++hh)
        gload_lds16(Vh + (size_t)(8 * w + srow) * SEQ + 64 * hh + cg * 8,
                    &Vs[0][hh][(8 * w) * 64]);

    // Q fragments: B-operand (n = query = l16, k = d = quad*8+j)
    bf16x8 qf[2];
#pragma unroll
    for (int ks = 0; ks < 2; ++ks)
        qf[ks] = *(const bf16x8*)(Qh + (size_t)(qbase + l16) * 64 + 32 * ks + quad * 8);

    // ---- precompute per-64-key-group dirty bitmask (no VMEM in main loop) ----
    unsigned dirty = 0;
#pragma unroll
    for (int i = 0; i < 8; ++i) {
        const int4 m4 = *(const int4*)(mrow + i * 256 + lane * 4);
        const bool ok = (m4.x != 0) & (m4.y != 0) & (m4.z != 0) & (m4.w != 0);
        const unsigned long long bal = __ballot(ok);
#pragma unroll
        for (int g = 0; g < 4; ++g)
            if (((bal >> (16 * g)) & 0xffffull) != 0xffffull) dirty |= 1u << (i * 4 + g);
    }

    f32x4 o[4];
#pragma unroll
    for (int id = 0; id < 4; ++id) o[id] = (f32x4){0.f, 0.f, 0.f, 0.f};
    float lst = 0.f;
    const f32x4 fzero = (f32x4){0.f, 0.f, 0.f, 0.f};
    const int rowsel = (lane & 48) | (quad * 4);

    union U { bf16x8 v; unsigned d[4]; };

#pragma unroll 2
    for (int kb = 0; kb < 16; ++kb) {
        const int cur = kb & 1;
        __syncthreads();  // drains stage(kb); all waves done with buf cur^1

        if (kb != 15) {   // stage kb+1 into the other buffer
            const int kn = (kb + 1) * 128;
#pragma unroll
            for (int t = 0; t < 2; ++t) {
                const int r = 16 * w + 8 * t + srow;
                gload_lds16(Kh + (size_t)(kn + r) * 64 + (scol ^ (r & 7)) * 8,
                            &Ks[cur ^ 1][(16 * w + 8 * t) * 64]);
            }
#pragma unroll
            for (int hh = 0; hh < 2; ++hh)
                gload_lds16(Vh + (size_t)(8 * w + srow) * SEQ + kn + 64 * hh + cg * 8,
                            &Vs[cur ^ 1][hh][(8 * w) * 64]);
        }

        const int kstart = kb * 128;
        const bool clean = ((dirty >> (2 * kb)) & 3u) == 0u;  // uniform, no VMEM

        // QK in two ik-halves (keeps kf at 32 VGPRs): S^T = K * Q^T, log2 dom.
        f32x4 s[8];
#pragma unroll
        for (int half = 0; half < 2; ++half) {
            bf16x8 kf[4][2];
#pragma unroll
            for (int i2 = 0; i2 < 4; ++i2) {
                const int row = 64 * half + 16 * i2 + l16;
#pragma unroll
                for (int ks = 0; ks < 2; ++ks)
                    kf[i2][ks] = *(const bf16x8*)&Ks[cur][row * 64 + ((4 * ks + quad) ^ (row & 7)) * 8];
            }
            __builtin_amdgcn_s_setprio(1);
#pragma unroll
            for (int i2 = 0; i2 < 4; ++i2) {
                f32x4 t = __builtin_amdgcn_mfma_f32_16x16x32_bf16(kf[i2][0], qf[0], fzero, 0, 0, 0);
                t = __builtin_amdgcn_mfma_f32_16x16x32_bf16(kf[i2][1], qf[1], t, 0, 0, 0);
                s[4 * half + i2] = t;
            }
            __builtin_amdgcn_s_setprio(0);
        }

        if (!clean) {  // rare: apply per-element mask fill (off hot path)
#pragma unroll
            for (int ik = 0; ik < 8; ++ik) {
                int4 mk = *(const int4*)(mrow + kstart + 16 * ik + quad * 4);
                const int* mp = (const int*)&mk;
#pragma unroll
                for (int r = 0; r < 4; ++r)
                    s[ik][r] = (mp[r] != 0) ? s[ik][r] : -1e9f;
            }
        }

        // p = exp2(s); pack to bf16 pair-dwords; accumulate row sums
        float rs = 0.f;
        unsigned c[8][2];
#pragma unroll
        for (int ik = 0; ik < 8; ++ik) {
            const float p0 = EXP2F(s[ik][0]);
            const float p1 = EXP2F(s[ik][1]);
            const float p2 = EXP2F(s[ik][2]);
            const float p3 = EXP2F(s[ik][3]);
            rs += (p0 + p1) + (p2 + p3);
            c[ik][0] = pkbf(p0, p1);
            c[ik][1] = pkbf(p2, p3);
        }
        rs += __shfl_xor(rs, 16, 64);
        rs += __shfl_xor(rs, 32, 64);
        lst += rs;

        // in-register P redistribution per ik-pair (verified R10/R11):
        // pair p = (c[2p], c[2p+1]) -> keys 32p..32p+31 as PV A-fragment
        U u[4];
#pragma unroll
        for (int p = 0; p < 4; ++p) {
            plswap32(c[2 * p][0], c[2 * p + 1][0]);
            plswap32(c[2 * p][1], c[2 * p + 1][1]);
            plswap16(c[2 * p][0], c[2 * p + 1][0]);
            plswap16(c[2 * p][1], c[2 * p + 1][1]);
            u[p].d[0] = c[2 * p][0]; u[p].d[1] = c[2 * p][1];
            u[p].d[2] = c[2 * p + 1][0]; u[p].d[3] = c[2 * p + 1][1];
        }

        // PV: A = u[ks4] (in-register), B = V fragments from the proven
        // 64-wide sub-tile layout: half h = ks4>>1, local ks = ks4&1
        __builtin_amdgcn_s_setprio(1);
#pragma unroll
        for (int ks4 = 0; ks4 < 4; ++ks4) {
            const int hh  = ks4 >> 1;
            const int ksw = ks4 & 1;
#pragma unroll
            for (int id = 0; id < 4; ++id) {
                const int row = 16 * id + l16;
                const bf16x8 vfr = *(const bf16x8*)&Vs[cur][hh][row * 64 + ((4 * ksw + quad) ^ (row & 7)) * 8];
                o[id] = __builtin_amdgcn_mfma_f32_16x16x32_bf16(u[ks4].v, vfr, o[id], 0, 0, 0);
            }
        }
        __builtin_amdgcn_s_setprio(0);
    }

    // epilogue: divide by softmax sum (l lives per-col -> remap to rows)
    float linv[4];
#pragma unroll
    for (int r = 0; r < 4; ++r) linv[r] = 1.f / __shfl(lst, rowsel + r, 64);
#pragma unroll
    for (int id = 0; id < 4; ++id)
#pragma unroll
        for (int r = 0; r < 4; ++r) {
            const int q = qbase + quad * 4 + r;
            const int d = 16 * id + l16;
            ctx[((size_t)(b * SEQ + q)) * D_MODEL + h * 64 + d] = f2bf(o[id][r] * linv[r]);
        }
}

// ---------------------------------------------------------------- launch
extern "C" void kernel_launch(void* const* d_in, const int* in_sizes, int n_in,
                              void* d_out, int out_size, void* d_ws, size_t ws_size,
                              hipStream_t stream) {
    const float* x    = (const float*)d_in[0];
    const int*   mask = (const int*)d_in[1];
    const float* Wq   = (const float*)d_in[2];
    const float* bq   = (const float*)d_in[3];
    const float* Wk   = (const float*)d_in[4];
    const float* bk   = (const float*)d_in[5];
    const float* Wv   = (const float*)d_in[6];
    const float* bv   = (const float*)d_in[7];
    const float* Wo   = (const float*)d_in[8];
    const float* bo   = (const float*)d_in[9];

    u16* xb  = (u16*)d_ws;                                   // [4096,1024]
    u16* wqb = xb  + (size_t)MROWS * D_MODEL;                // [3072,1024] fused W_qkv
    u16* wob = wqb + (size_t)3 * D_MODEL * D_MODEL;          // [1024,1024]
    u16* Qb  = wob + (size_t)D_MODEL * D_MODEL;              // [B,H,S,64]
    u16* Kb  = Qb  + (size_t)MROWS * D_MODEL;
    u16* VTb = Kb  + (size_t)MROWS * D_MODEL;                // [B,H,64,S]
    u16* ctx = VTb + (size_t)MROWS * D_MODEL;                // [B,S,D]

    // one conversion launch: x (4x1M) + Wq/Wk/Wv/Wo (1M each), contiguous dst
    cvt_all<<<dim3(D_MODEL * D_MODEL / 1024, 8), 256, 0, stream>>>(
        x, Wq, Wk, Wv, Wo, xb);

    // fused QKV projection: N = 3072; V written transposed directly to VTb
    gemm_staged<128, 0><<<dim3(3 * D_MODEL / 128, MROWS / 128), 256, 0, stream>>>(
        xb, wqb, bq, bk, bv, Qb, Kb, VTb, nullptr, D_MODEL, 3 * D_MODEL);

    // 8-wave blocks, 128 q-rows each: 32 bh x 16 q-blocks = 512 blocks (2/CU)
    attn_kernel<<<BATCH * NUM_HEADS * (SEQ / 128), 512, 0, stream>>>(Qb, Kb, VTb, mask, ctx);

    // final projection: BN 64 -> 128 (m92/m103 tile ladder: 64-wide ~343 TF
    // vs 128-wide ~912 TF at this structure). 8x32 = 256 blocks.
    gemm_staged<128, 1><<<dim3(D_MODEL / 128, MROWS / 128), 256, 0, stream>>>(
        ctx, wob, bo, nullptr, nullptr, nullptr, nullptr, nullptr,
        (float*)d_out, D_MODEL, D_MODEL);
}

// Round 14
// 185.473 us; speedup vs baseline: 1.0639x; 1.0639x over previous
//
#include <hip/hip_runtime.h>
#include <hip/hip_bf16.h>
#include <cstdint>

#define D_MODEL 1024
#define NUM_HEADS 16
#define HEAD_DIM 64
#define BATCH 2
#define SEQ 2048
#define MROWS (BATCH * SEQ)  // 4096

typedef __attribute__((ext_vector_type(8))) short bf16x8;   // 8 bf16 in 4 VGPRs
typedef __attribute__((ext_vector_type(4))) float f32x4;
typedef __attribute__((ext_vector_type(2))) unsigned u32x2;
typedef unsigned short u16;

// Q is pre-scaled by 0.125 * log2(e) at the QKV epilogue, so attention scores
// come out of the MFMA already in log2 domain: p = exp2(s) directly.
#define QSCALE (0.125f * 1.44269504f)

#if __has_builtin(__builtin_amdgcn_exp2f)
#define EXP2F(x) __builtin_amdgcn_exp2f(x)
#else
#define EXP2F(x) exp2f(x)
#endif

static __device__ __forceinline__ u16 f2bf(float f) {
    unsigned int u = __float_as_uint(f);
    unsigned int lsb = (u >> 16) & 1u;
    u += 0x7fffu + lsb;
    return (u16)(u >> 16);
}

// pack two fp32 -> two bf16 in one dword
#if __has_builtin(__builtin_amdgcn_cvt_pk_bf16_f32)
static __device__ __forceinline__ unsigned pkbf(float a, float b) {
    typedef __attribute__((ext_vector_type(2))) __bf16 bf2;
    union { bf2 v; unsigned u; } cv;
    cv.v = __builtin_amdgcn_cvt_pk_bf16_f32(a, b);
    return cv.u;
}
#else
static __device__ __forceinline__ unsigned pkbf(float a, float b) {
    unsigned ua = (__float_as_uint(a) + 0x8000u) >> 16;
    unsigned ub = (__float_as_uint(b) + 0x8000u) & 0xffff0000u;
    return ua | ub;
}
#endif

// ---- lane-quad swaps for in-register P redistribution (verified R10/R11) ----
// permlane32_swap: a' = [a0,a1,b0,b1] (by 16-lane quads), b' = [a2,a3,b2,b3]
// permlane16_swap: a' = [a0,b0,a2,b2],                    b' = [a1,b1,a3,b3]
#if __has_builtin(__builtin_amdgcn_permlane32_swap)
static __device__ __forceinline__ void plswap32(unsigned &a, unsigned &b) {
    u32x2 r = __builtin_amdgcn_permlane32_swap(a, b, false, false);
    a = r[0]; b = r[1];
}
#else
static __device__ __forceinline__ void plswap32(unsigned &a, unsigned &b) {
    const bool lo = ((threadIdx.x & 63) < 32);
    unsigned sa = __shfl_xor((int)a, 32, 64), sb = __shfl_xor((int)b, 32, 64);
    unsigned na = lo ? a : sb;
    unsigned nb = lo ? sa : b;
    a = na; b = nb;
}
#endif
#if __has_builtin(__builtin_amdgcn_permlane16_swap)
static __device__ __forceinline__ void plswap16(unsigned &a, unsigned &b) {
    u32x2 r = __builtin_amdgcn_permlane16_swap(a, b, false, false);
    a = r[0]; b = r[1];
}
#else
static __device__ __forceinline__ void plswap16(unsigned &a, unsigned &b) {
    const bool ev = (((threadIdx.x & 63) >> 4) & 1) == 0;
    unsigned sa = __shfl_xor((int)a, 16, 64), sb = __shfl_xor((int)b, 16, 64);
    unsigned na = ev ? a : sb;
    unsigned nb = ev ? sa : b;
    a = na; b = nb;
}
#endif

static __device__ __forceinline__ void gload_lds16(const void* g, void* l) {
    // 16B/lane direct global->LDS; LDS dest = wave-uniform base + lane*16
    __builtin_amdgcn_global_load_lds((const __attribute__((address_space(1))) unsigned int*)g,
                                     (__attribute__((address_space(3))) unsigned int*)l,
                                     16, 0, 0);
}

// ---------------------------------------------------------------- convert
__global__ void cvt_all(const float* __restrict__ x,
                        const float* __restrict__ w0, const float* __restrict__ w1,
                        const float* __restrict__ w2, const float* __restrict__ w3,
                        u16* __restrict__ base) {
    const int which = blockIdx.y;   // 0..7
    const int NE = D_MODEL * D_MODEL;  // 1M elements per chunk
    const float* s;
    if (which < 4)      s = x + (size_t)which * NE;
    else if (which == 4) s = w0;
    else if (which == 5) s = w1;
    else if (which == 6) s = w2;
    else                 s = w3;
    u16* dst = base + (size_t)which * NE;
    const int i = (blockIdx.x * blockDim.x + threadIdx.x) * 4;
    float4 v = *(const float4*)(s + i);
    ushort4 o;
    o.x = f2bf(v.x); o.y = f2bf(v.y); o.z = f2bf(v.z); o.w = f2bf(v.w);
    *(ushort4*)(dst + i) = o;
}

// ---------------------------------------------------------------- staged GEMM
// C[M,N] = A[M,K] * W[N,K]^T + bias. 128xBN tile, BK=64, global_load_lds
// staging with 16B-chunk XOR swizzle.
// MODE 0 (BN=128, fused QKV, N=3072): blocks 0-7 -> Q (pre-scaled, coalesced
// [B,H,S,64]), 8-15 -> K (coalesced), 16-23 -> V written TRANSPOSED to
// VT[B,H,64,S] via an in-LDS 128x128 transpose (two 64-row passes).
// MODE 1 (BN=64): fp32 row-major out (final projection). At N=1024 the
// 64-wide tile with 512 blocks (2/CU) beats 128-wide with 256 blocks (1/CU):
// occupancy dominates tile width when the grid is this small (R19 lesson).
template<int BN, int MODE>
__global__ __launch_bounds__(256, 3)
void gemm_staged(const u16* __restrict__ A, const u16* __restrict__ W,
                 const float* __restrict__ b0, const float* __restrict__ b1,
                 const float* __restrict__ b2,
                 u16* __restrict__ o0, u16* __restrict__ o1, u16* __restrict__ o2,
                 float* __restrict__ of, int K, int N) {
    constexpr int WN = BN / 2;   // per-wave n extent
    constexpr int NJ = WN / 16;  // b-fragment count
    __shared__ __align__(16) u16 As[128 * 64];
    __shared__ __align__(16) u16 Bs[BN * 64];
    __shared__ __align__(16) u16 T[(MODE == 0) ? 64 * 136 : 16];  // V-transpose staging

    const int lane = threadIdx.x & 63;
    const int w    = threadIdx.x >> 6;
    const int quad = lane >> 4;
    const int l16  = lane & 15;
    const int wm = w >> 1, wn = w & 1;

    const u16* Ablk = A + (size_t)(blockIdx.y * 128) * K;
    const u16* Wblk = W + (size_t)(blockIdx.x * BN) * K;

    const int srow = lane >> 3;
    const int scol = lane & 7;

    f32x4 acc[4][NJ];
#pragma unroll
    for (int i = 0; i < 4; ++i)
#pragma unroll
        for (int j = 0; j < NJ; ++j) acc[i][j] = (f32x4){0.f, 0.f, 0.f, 0.f};

    for (int kb0 = 0; kb0 < K; kb0 += 64) {
        __syncthreads();
#pragma unroll
        for (int t = 0; t < 4; ++t) {  // A: 128 rows
            const int r  = w * 32 + t * 8 + srow;
            const int cg = scol ^ (r & 7);
            gload_lds16(Ablk + (size_t)r * K + kb0 + cg * 8, &As[(w * 32 + t * 8) * 64]);
        }
#pragma unroll
        for (int t = 0; t < BN / 32; ++t) {  // B: BN rows
            const int r  = w * (BN / 4) + t * 8 + srow;
            const int cg = scol ^ (r & 7);
            gload_lds16(Wblk + (size_t)r * K + kb0 + cg * 8, &Bs[(w * (BN / 4) + t * 8) * 64]);
        }
        __syncthreads();
#pragma unroll
        for (int ks = 0; ks < 2; ++ks) {
            bf16x8 a[4], b[NJ];
#pragma unroll
            for (int i = 0; i < 4; ++i) {
                const int ra = wm * 64 + 16 * i + l16;
                a[i] = *(const bf16x8*)&As[ra * 64 + ((ks * 4 + quad) ^ (ra & 7)) * 8];
            }
#pragma unroll
            for (int j = 0; j < NJ; ++j) {
                const int rb = wn * WN + 16 * j + l16;
                b[j] = *(const bf16x8*)&Bs[rb * 64 + ((ks * 4 + quad) ^ (rb & 7)) * 8];
            }
#pragma unroll
            for (int i = 0; i < 4; ++i)
#pragma unroll
                for (int j = 0; j < NJ; ++j)
                    acc[i][j] = __builtin_amdgcn_mfma_f32_16x16x32_bf16(a[i], b[j], acc[i][j], 0, 0, 0);
        }
    }

    const int mbase = blockIdx.y * 128 + wm * 64;
    const int nbase = blockIdx.x * BN + wn * WN;

    if (MODE == 0 && blockIdx.x >= 16) {
        // ---- V block: write VT[b][h][d][s] via in-LDS transpose ----
        const int mb    = blockIdx.y * 128;
        const int bb    = mb >> 11;        // batch (uniform per block)
        const int sbase = mb & 2047;       // s-range start (uniform)
#pragma unroll
        for (int p = 0; p < 2; ++p) {      // n-half pass
            __syncthreads();               // T free / previous pass consumed
            if (wn == p) {                 // 2 waves own this n-half
#pragma unroll
                for (int j = 0; j < NJ; ++j) {
                    const int nl = 16 * j + l16;          // local n within half
                    const float bv = b2[(nbase + 16 * j + l16) & 1023];
#pragma unroll
                    for (int i = 0; i < 4; ++i) {
                        const int ml = wm * 64 + 16 * i + quad * 4;
                        uint2 pk;
                        pk.x = pkbf(acc[i][j][0] + bv, acc[i][j][1] + bv);
                        pk.y = pkbf(acc[i][j][2] + bv, acc[i][j][3] + bv);
                        *(uint2*)&T[nl * 136 + ml] = pk;
                    }
                }
            }
            __syncthreads();
            // cooperative coalesced out: 64 rows (d) x 128 s; 256B/row
            const int row = threadIdx.x >> 2;                       // 0..63
            const int gn2 = blockIdx.x * 128 + p * 64 + row;
            const int rem2 = gn2 & 1023;
            const int h = rem2 >> 6, d = rem2 & 63;
            u16* dstrow = o2 + (((size_t)(bb * NUM_HEADS + h) * 64) + d) * SEQ + sbase;
#pragma unroll
            for (int k = 0; k < 4; ++k) {
                const int chunk = (threadIdx.x & 3) * 4 + k;        // 0..15
                *(uint4*)(dstrow + chunk * 8) = *(const uint4*)&T[row * 136 + chunk * 8];
            }
        }
        return;
    }

    if (MODE == 0) {
#pragma unroll
        for (int j = 0; j < NJ; ++j) {
            const int gn = nbase + 16 * j + l16;       // 0..2047 here (Q or K)
            const int which = gn >> 10, rem = gn & 1023;
            const float bv = (which == 0 ? b0 : b1)[rem];
            u16* dst = (which == 0) ? o0 : o1;
            const float scl = (which == 0) ? QSCALE : 1.0f;  // Q: x0.125*log2e
            const int h = rem >> 6, d = rem & 63;
#pragma unroll
            for (int i = 0; i < 4; ++i)
#pragma unroll
                for (int r = 0; r < 4; ++r) {
                    const int gm = mbase + 16 * i + quad * 4 + r;
                    const int bb = gm >> 11, s = gm & 2047;
                    dst[(((size_t)(bb * NUM_HEADS + h) * SEQ) + s) * 64 + d] =
                        f2bf((acc[i][j][r] + bv) * scl);
                }
        }
    } else {
#pragma unroll
        for (int j = 0; j < NJ; ++j) {
            const int gn = nbase + 16 * j + l16;
            const float bv = b0[gn];
#pragma unroll
            for (int i = 0; i < 4; ++i)
#pragma unroll
                for (int r = 0; r < 4; ++r) {
                    const int gm = mbase + 16 * i + quad * 4 + r;
                    of[(size_t)gm * N + gn] = acc[i][j][r] + bv;
                }
        }
    }
}

// ---------------------------------------------------------------- attention
// FINAL = R17 (measured best: ~56us, 0 bank conflicts, VGPR 64).
// Attn is FROZEN: nine structural experiments (R7-R18: occupancy x2/x0.5,
// LDS reads x0.5, 2x pipeline attempts, barriers x0.5, conflicts +-4M,
// MFMA chain splits) all land at 56-72us -- latency-plateau at HIP source
// level (MfmaUtil ~24, VALU ~47, HBM ~4.7%). Remaining gap is co-designed
// schedule territory (T16), not single-lever.
// KVBLK=128 (16 tiles), K in 128B-row XOR-swizzled layout, V as two 64-key
// sub-tiles in R11's proven conflict-free layout. In-reg P via cvt_pk +
// permlane swaps, dirty bitmask (no VMEM in loop), no-clamp exp2, setprio.
__global__ __launch_bounds__(512, 4)
void attn_kernel(const u16* __restrict__ Q, const u16* __restrict__ K,
                 const u16* __restrict__ VT, const int* __restrict__ mask,
                 u16* __restrict__ ctx) {
    __shared__ __align__(16) u16 Ks[2][128 * 64];     // 128 keys x 64 d (128B rows)
    __shared__ __align__(16) u16 Vs[2][2][64 * 64];   // [buf][key-half]: 64 d x 64 keys

    const int lane = threadIdx.x & 63;
    const int w    = threadIdx.x >> 6;   // 0..7
    const int quad = lane >> 4;
    const int l16  = lane & 15;

    const int bh = blockIdx.x & 31;   // same-head q-blocks share an XCD's L2
    const int qb = blockIdx.x >> 5;   // 0..15
    const int b  = bh >> 4;
    const int h  = bh & 15;
    const int qbase = qb * 128 + w * 16;

    const u16* Qh = Q + (size_t)bh * SEQ * 64;
    const u16* Kh = K + (size_t)bh * SEQ * 64;
    const u16* Vh = VT + (size_t)bh * 64 * SEQ;
    const int* mrow = mask + b * SEQ;

    const int srow = lane >> 3;   // row within an 8-row staging group
    const int scol = lane & 7;    // stored 16B chunk slot (8 per 128B row)
    const int cg   = scol ^ srow; // global chunk for XOR-swizzled slot

    // ---- stage tile kb=0 into buffer 0 ----
    // K: wave w stages key-rows 16w..16w+15 (2 instr, R11 row pattern)
#pragma unroll
    for (int t = 0; t < 2; ++t) {
        const int r = 16 * w + 8 * t + srow;
        gload_lds16(Kh + (size_t)r * 64 + (scol ^ (r & 7)) * 8,
                    &Ks[0][(16 * w + 8 * t) * 64]);
    }
    // V: wave w stages d-rows 8w..8w+7 of each 64-key half (R11 exact pattern)
#pragma unroll
    for (int hh = 0; hh < 2; ++hh)
        gload_lds16(Vh + (size_t)(8 * w + srow) * SEQ + 64 * hh + cg * 8,
                    &Vs[0][hh][(8 * w) * 64]);

    // Q fragments: B-operand (n = query = l16, k = d = quad*8+j)
    bf16x8 qf[2];
#pragma unroll
    for (int ks = 0; ks < 2; ++ks)
        qf[ks] = *(const bf16x8*)(Qh + (size_t)(qbase + l16) * 64 + 32 * ks + quad * 8);

    // ---- precompute per-64-key-group dirty bitmask (no VMEM in main loop) ----
    unsigned dirty = 0;
#pragma unroll
    for (int i = 0; i < 8; ++i) {
        const int4 m4 = *(const int4*)(mrow + i * 256 + lane * 4);
        const bool ok = (m4.x != 0) & (m4.y != 0) & (m4.z != 0) & (m4.w != 0);
        const unsigned long long bal = __ballot(ok);
#pragma unroll
        for (int g = 0; g < 4; ++g)
            if (((bal >> (16 * g)) & 0xffffull) != 0xffffull) dirty |= 1u << (i * 4 + g);
    }

    f32x4 o[4];
#pragma unroll
    for (int id = 0; id < 4; ++id) o[id] = (f32x4){0.f, 0.f, 0.f, 0.f};
    float lst = 0.f;
    const f32x4 fzero = (f32x4){0.f, 0.f, 0.f, 0.f};
    const int rowsel = (lane & 48) | (quad * 4);

    union U { bf16x8 v; unsigned d[4]; };

#pragma unroll 2
    for (int kb = 0; kb < 16; ++kb) {
        const int cur = kb & 1;
        __syncthreads();  // drains stage(kb); all waves done with buf cur^1

        if (kb != 15) {   // stage kb+1 into the other buffer
            const int kn = (kb + 1) * 128;
#pragma unroll
            for (int t = 0; t < 2; ++t) {
                const int r = 16 * w + 8 * t + srow;
                gload_lds16(Kh + (size_t)(kn + r) * 64 + (scol ^ (r & 7)) * 8,
                            &Ks[cur ^ 1][(16 * w + 8 * t) * 64]);
            }
#pragma unroll
            for (int hh = 0; hh < 2; ++hh)
                gload_lds16(Vh + (size_t)(8 * w + srow) * SEQ + kn + 64 * hh + cg * 8,
                            &Vs[cur ^ 1][hh][(8 * w) * 64]);
        }

        const int kstart = kb * 128;
        const bool clean = ((dirty >> (2 * kb)) & 3u) == 0u;  // uniform, no VMEM

        // QK in two ik-halves (keeps kf at 32 VGPRs): S^T = K * Q^T, log2 dom.
        f32x4 s[8];
#pragma unroll
        for (int half = 0; half < 2; ++half) {
            bf16x8 kf[4][2];
#pragma unroll
            for (int i2 = 0; i2 < 4; ++i2) {
                const int row = 64 * half + 16 * i2 + l16;
#pragma unroll
                for (int ks = 0; ks < 2; ++ks)
                    kf[i2][ks] = *(const bf16x8*)&Ks[cur][row * 64 + ((4 * ks + quad) ^ (row & 7)) * 8];
            }
            __builtin_amdgcn_s_setprio(1);
#pragma unroll
            for (int i2 = 0; i2 < 4; ++i2) {
                f32x4 t = __builtin_amdgcn_mfma_f32_16x16x32_bf16(kf[i2][0], qf[0], fzero, 0, 0, 0);
                t = __builtin_amdgcn_mfma_f32_16x16x32_bf16(kf[i2][1], qf[1], t, 0, 0, 0);
                s[4 * half + i2] = t;
            }
            __builtin_amdgcn_s_setprio(0);
        }

        if (!clean) {  // rare: apply per-element mask fill (off hot path)
#pragma unroll
            for (int ik = 0; ik < 8; ++ik) {
                int4 mk = *(const int4*)(mrow + kstart + 16 * ik + quad * 4);
                const int* mp = (const int*)&mk;
#pragma unroll
                for (int r = 0; r < 4; ++r)
                    s[ik][r] = (mp[r] != 0) ? s[ik][r] : -1e9f;
            }
        }

        // p = exp2(s); pack to bf16 pair-dwords; accumulate row sums
        float rs = 0.f;
        unsigned c[8][2];
#pragma unroll
        for (int ik = 0; ik < 8; ++ik) {
            const float p0 = EXP2F(s[ik][0]);
            const float p1 = EXP2F(s[ik][1]);
            const float p2 = EXP2F(s[ik][2]);
            const float p3 = EXP2F(s[ik][3]);
            rs += (p0 + p1) + (p2 + p3);
            c[ik][0] = pkbf(p0, p1);
            c[ik][1] = pkbf(p2, p3);
        }
        rs += __shfl_xor(rs, 16, 64);
        rs += __shfl_xor(rs, 32, 64);
        lst += rs;

        // in-register P redistribution per ik-pair (verified R10/R11):
        // pair p = (c[2p], c[2p+1]) -> keys 32p..32p+31 as PV A-fragment
        U u[4];
#pragma unroll
        for (int p = 0; p < 4; ++p) {
            plswap32(c[2 * p][0], c[2 * p + 1][0]);
            plswap32(c[2 * p][1], c[2 * p + 1][1]);
            plswap16(c[2 * p][0], c[2 * p + 1][0]);
            plswap16(c[2 * p][1], c[2 * p + 1][1]);
            u[p].d[0] = c[2 * p][0]; u[p].d[1] = c[2 * p][1];
            u[p].d[2] = c[2 * p + 1][0]; u[p].d[3] = c[2 * p + 1][1];
        }

        // PV: A = u[ks4] (in-register), B = V fragments from the proven
        // 64-wide sub-tile layout: half h = ks4>>1, local ks = ks4&1
        __builtin_amdgcn_s_setprio(1);
#pragma unroll
        for (int ks4 = 0; ks4 < 4; ++ks4) {
            const int hh  = ks4 >> 1;
            const int ksw = ks4 & 1;
#pragma unroll
            for (int id = 0; id < 4; ++id) {
                const int row = 16 * id + l16;
                const bf16x8 vfr = *(const bf16x8*)&Vs[cur][hh][row * 64 + ((4 * ksw + quad) ^ (row & 7)) * 8];
                o[id] = __builtin_amdgcn_mfma_f32_16x16x32_bf16(u[ks4].v, vfr, o[id], 0, 0, 0);
            }
        }
        __builtin_amdgcn_s_setprio(0);
    }

    // epilogue: divide by softmax sum (l lives per-col -> remap to rows)
    float linv[4];
#pragma unroll
    for (int r = 0; r < 4; ++r) linv[r] = 1.f / __shfl(lst, rowsel + r, 64);
#pragma unroll
    for (int id = 0; id < 4; ++id)
#pragma unroll
        for (int r = 0; r < 4; ++r) {
            const int q = qbase + quad * 4 + r;
            const int d = 16 * id + l16;
            ctx[((size_t)(b * SEQ + q)) * D_MODEL + h * 64 + d] = f2bf(o[id][r] * linv[r]);
        }
}

// ---------------------------------------------------------------- launch
extern "C" void kernel_launch(void* const* d_in, const int* in_sizes, int n_in,
                              void* d_out, int out_size, void* d_ws, size_t ws_size,
                              hipStream_t stream) {
    const float* x    = (const float*)d_in[0];
    const int*   mask = (const int*)d_in[1];
    const float* Wq   = (const float*)d_in[2];
    const float* bq   = (const float*)d_in[3];
    const float* Wk   = (const float*)d_in[4];
    const float* bk   = (const float*)d_in[5];
    const float* Wv   = (const float*)d_in[6];
    const float* bv   = (const float*)d_in[7];
    const float* Wo   = (const float*)d_in[8];
    const float* bo   = (const float*)d_in[9];

    u16* xb  = (u16*)d_ws;                                   // [4096,1024]
    u16* wqb = xb  + (size_t)MROWS * D_MODEL;                // [3072,1024] fused W_qkv
    u16* wob = wqb + (size_t)3 * D_MODEL * D_MODEL;          // [1024,1024]
    u16* Qb  = wob + (size_t)D_MODEL * D_MODEL;              // [B,H,S,64]
    u16* Kb  = Qb  + (size_t)MROWS * D_MODEL;
    u16* VTb = Kb  + (size_t)MROWS * D_MODEL;                // [B,H,64,S]
    u16* ctx = VTb + (size_t)MROWS * D_MODEL;                // [B,S,D]

    // one conversion launch: x (4x1M) + Wq/Wk/Wv/Wo (1M each), contiguous dst
    cvt_all<<<dim3(D_MODEL * D_MODEL / 1024, 8), 256, 0, stream>>>(
        x, Wq, Wk, Wv, Wo, xb);

    // fused QKV projection: N = 3072; V written transposed directly to VTb
    gemm_staged<128, 0><<<dim3(3 * D_MODEL / 128, MROWS / 128), 256, 0, stream>>>(
        xb, wqb, bq, bk, bv, Qb, Kb, VTb, nullptr, D_MODEL, 3 * D_MODEL);

    // 8-wave blocks, 128 q-rows each: 32 bh x 16 q-blocks = 512 blocks (2/CU)
    attn_kernel<<<BATCH * NUM_HEADS * (SEQ / 128), 512, 0, stream>>>(Qb, Kb, VTb, mask, ctx);

    // final projection: BN=64, 512 blocks (2/CU) -- at N=1024 occupancy beats
    // tile width (BN=128 @ 256 blocks = 1 block/CU regressed, R19 lesson)
    gemm_staged<64, 1><<<dim3(D_MODEL / 64, MROWS / 128), 256, 0, stream>>>(
        ctx, wob, bo, nullptr, nullptr, nullptr, nullptr, nullptr,
        (float*)d_out, D_MODEL, D_MODEL);
}